// Round 1
// baseline (833.457 us; speedup 1.0000x reference)
//
#include <hip/hip_runtime.h>

typedef unsigned short u16;
typedef float f32x4 __attribute__((ext_vector_type(4)));
typedef short s16x8 __attribute__((ext_vector_type(8)));

#define DEV static __device__ __forceinline__

DEV u16 f2bf(float f){
  unsigned u = __float_as_uint(f);
  u += 0x7fffu + ((u>>16)&1u);
  return (u16)(u>>16);
}

DEV f32x4 mfma_bf16(s16x8 a, s16x8 b, f32x4 c){
  return __builtin_amdgcn_mfma_f32_16x16x32_bf16(a, b, c, 0, 0, 0);
}

// ---------------- transpose + cast: w [K][N] f32 -> wt [N][K] bf16 ----------
__global__ __launch_bounds__(256) void transpose_cast(const float* __restrict__ w,
                                                      u16* __restrict__ wt,
                                                      int K, int N){
  __shared__ float tile[32][33];
  int n0 = blockIdx.x * 32, k0 = blockIdx.y * 32;
  int tx = threadIdx.x & 31, ty = threadIdx.x >> 5;   // 32 x 8
  #pragma unroll
  for(int j = 0; j < 32; j += 8)
    tile[ty + j][tx] = w[(size_t)(k0 + ty + j) * N + n0 + tx];
  __syncthreads();
  #pragma unroll
  for(int j = 0; j < 32; j += 8)
    wt[(size_t)(n0 + ty + j) * K + k0 + tx] = f2bf(tile[tx][ty + j]);
}

// ---------------- QKV projection (per-head 64x64, shared weights) -----------
// x [B*S][1024] f32 -> q/k/v [B][H][S][64] bf16
__global__ __launch_bounds__(256) void qkv_kernel(const float* __restrict__ x,
    const float* __restrict__ wq, const float* __restrict__ bq,
    const float* __restrict__ wk, const float* __restrict__ bk,
    const float* __restrict__ wv, const float* __restrict__ bv,
    u16* __restrict__ qo, u16* __restrict__ ko, u16* __restrict__ vo){
  __shared__ float ws[3 * 64 * 64];   // 48 KiB
  __shared__ float xs[32 * 64];       // 8 KiB
  int h  = blockIdx.y;
  int r0 = blockIdx.x * 32;           // global row base (over B*S)
  for(int i = threadIdx.x; i < 1024; i += 256) ((float4*)ws)[i]        = ((const float4*)wq)[i];
  for(int i = threadIdx.x; i < 1024; i += 256) ((float4*)ws)[1024 + i] = ((const float4*)wk)[i];
  for(int i = threadIdx.x; i < 1024; i += 256) ((float4*)ws)[2048 + i] = ((const float4*)wv)[i];
  for(int i = threadIdx.x; i < 512; i += 256){
    int r = i >> 4, c4 = (i & 15) * 4;
    ((float4*)xs)[i] = *(const float4*)(x + (size_t)(r0 + r) * 1024 + h * 64 + c4);
  }
  __syncthreads();
  int r  = threadIdx.x >> 3;
  int j0 = (threadIdx.x & 7) * 8;
  float aq[8], ak[8], av[8];
  #pragma unroll
  for(int j = 0; j < 8; j++){ aq[j] = 0.f; ak[j] = 0.f; av[j] = 0.f; }
  for(int i = 0; i < 64; i++){
    float xv = xs[r * 64 + i];
    const float* wr = ws + i * 64 + j0;
    #pragma unroll
    for(int j = 0; j < 8; j++){
      aq[j] = fmaf(xv, wr[j],        aq[j]);
      ak[j] = fmaf(xv, wr[4096 + j], ak[j]);
      av[j] = fmaf(xv, wr[8192 + j], av[j]);
    }
  }
  int g = r0 + r, b = g >> 11, s = g & 2047;
  size_t base = ((size_t)(b * 16 + h) * 2048 + s) * 64 + j0;
  ushort4 q_lo = { f2bf(aq[0]+bq[j0+0]), f2bf(aq[1]+bq[j0+1]), f2bf(aq[2]+bq[j0+2]), f2bf(aq[3]+bq[j0+3]) };
  ushort4 q_hi = { f2bf(aq[4]+bq[j0+4]), f2bf(aq[5]+bq[j0+5]), f2bf(aq[6]+bq[j0+6]), f2bf(aq[7]+bq[j0+7]) };
  ushort4 k_lo = { f2bf(ak[0]+bk[j0+0]), f2bf(ak[1]+bk[j0+1]), f2bf(ak[2]+bk[j0+2]), f2bf(ak[3]+bk[j0+3]) };
  ushort4 k_hi = { f2bf(ak[4]+bk[j0+4]), f2bf(ak[5]+bk[j0+5]), f2bf(ak[6]+bk[j0+6]), f2bf(ak[7]+bk[j0+7]) };
  ushort4 v_lo = { f2bf(av[0]+bv[j0+0]), f2bf(av[1]+bv[j0+1]), f2bf(av[2]+bv[j0+2]), f2bf(av[3]+bv[j0+3]) };
  ushort4 v_hi = { f2bf(av[4]+bv[j0+4]), f2bf(av[5]+bv[j0+5]), f2bf(av[6]+bv[j0+6]), f2bf(av[7]+bv[j0+7]) };
  *(ushort4*)(qo + base)     = q_lo;  *(ushort4*)(qo + base + 4) = q_hi;
  *(ushort4*)(ko + base)     = k_lo;  *(ushort4*)(ko + base + 4) = k_hi;
  *(ushort4*)(vo + base)     = v_lo;  *(ushort4*)(vo + base + 4) = v_hi;
}

// ---------------- flash attention, causal, bf16 MFMA ------------------------
// q/k/v [B*H][2048][64] bf16 -> o [B*S][1024] bf16 (head-interleaved)
__global__ __launch_bounds__(256) void attn_kernel(const u16* __restrict__ q,
                                                   const u16* __restrict__ k,
                                                   const u16* __restrict__ v,
                                                   u16* __restrict__ o){
  __shared__ u16 ks[64 * 64];
  __shared__ u16 vts[64 * 64];
  __shared__ u16 ps[4][16 * 64];
  int qt = blockIdx.x, bh = blockIdx.y;
  int tid = threadIdx.x, lane = tid & 63, w = tid >> 6;
  size_t kvbase = (size_t)bh * 2048 * 64;
  int l15 = lane & 15, l4 = lane >> 4;

  int qrow_g = qt * 64 + w * 16 + l15;
  s16x8 qf0 = *(const s16x8*)(q + kvbase + (size_t)qrow_g * 64 + l4 * 8);
  s16x8 qf1 = *(const s16x8*)(q + kvbase + (size_t)qrow_g * 64 + 32 + l4 * 8);

  f32x4 accO[4];
  f32x4 zero = {0.f, 0.f, 0.f, 0.f};
  #pragma unroll
  for(int n = 0; n < 4; n++) accO[n] = zero;
  float mrow[4], lrow[4];
  #pragma unroll
  for(int b = 0; b < 4; b++){ mrow[b] = -__builtin_inff(); lrow[b] = 0.f; }

  int nkt = qt + 1;
  for(int kt = 0; kt < nkt; kt++){
    __syncthreads();
    for(int c = tid; c < 512; c += 256){
      int row = c >> 3, c8 = (c & 7) * 8;
      uint4 kv4 = *(const uint4*)(k + kvbase + (size_t)(kt * 64 + row) * 64 + c8);
      *(uint4*)(ks + row * 64 + c8) = kv4;
      uint4 vv4 = *(const uint4*)(v + kvbase + (size_t)(kt * 64 + row) * 64 + c8);
      const u16* pu = (const u16*)&vv4;
      #pragma unroll
      for(int j = 0; j < 8; j++) vts[(c8 + j) * 64 + row] = pu[j];
    }
    __syncthreads();

    // scores: S = Q K^T / 8
    f32x4 sc[4];
    #pragma unroll
    for(int n = 0; n < 4; n++){
      f32x4 a = zero;
      s16x8 kf0 = *(const s16x8*)(ks + (n * 16 + l15) * 64 + l4 * 8);
      s16x8 kf1 = *(const s16x8*)(ks + (n * 16 + l15) * 64 + 32 + l4 * 8);
      a = mfma_bf16(qf0, kf0, a);
      a = mfma_bf16(qf1, kf1, a);
      sc[n] = a * 0.125f;
    }
    if(kt == qt){
      #pragma unroll
      for(int n = 0; n < 4; n++){
        int colg = kt * 64 + n * 16 + l15;
        #pragma unroll
        for(int b = 0; b < 4; b++){
          int rowg = qt * 64 + w * 16 + l4 * 4 + b;
          if(colg > rowg) sc[n][b] = -__builtin_inff();
        }
      }
    }
    // online softmax (rows live in 16-lane groups)
    float pex[4][4];
    #pragma unroll
    for(int b = 0; b < 4; b++){
      float tm_ = fmaxf(fmaxf(sc[0][b], sc[1][b]), fmaxf(sc[2][b], sc[3][b]));
      tm_ = fmaxf(tm_, __shfl_xor(tm_, 1));
      tm_ = fmaxf(tm_, __shfl_xor(tm_, 2));
      tm_ = fmaxf(tm_, __shfl_xor(tm_, 4));
      tm_ = fmaxf(tm_, __shfl_xor(tm_, 8));
      float mnew  = fmaxf(mrow[b], tm_);
      float alpha = expf(mrow[b] - mnew);
      mrow[b] = mnew;
      float rs = 0.f;
      #pragma unroll
      for(int n = 0; n < 4; n++){ pex[n][b] = expf(sc[n][b] - mnew); rs += pex[n][b]; }
      rs += __shfl_xor(rs, 1);
      rs += __shfl_xor(rs, 2);
      rs += __shfl_xor(rs, 4);
      rs += __shfl_xor(rs, 8);
      lrow[b] = lrow[b] * alpha + rs;
      #pragma unroll
      for(int n = 0; n < 4; n++) accO[n][b] *= alpha;
    }
    // P -> LDS (D-layout) then reread as A-frag
    #pragma unroll
    for(int n = 0; n < 4; n++)
      #pragma unroll
      for(int b = 0; b < 4; b++)
        ps[w][(l4 * 4 + b) * 64 + n * 16 + l15] = f2bf(pex[n][b]);
    asm volatile("s_waitcnt lgkmcnt(0)" ::: "memory");
    #pragma unroll
    for(int kc = 0; kc < 2; kc++){
      s16x8 pf = *(const s16x8*)(&ps[w][0] + l15 * 64 + kc * 32 + l4 * 8);
      #pragma unroll
      for(int n = 0; n < 4; n++){
        s16x8 vf = *(const s16x8*)(vts + (n * 16 + l15) * 64 + kc * 32 + l4 * 8);
        accO[n] = mfma_bf16(pf, vf, accO[n]);
      }
    }
  }
  // epilogue: normalize, write o
  int b_ = bh >> 4, h = bh & 15;
  #pragma unroll
  for(int n = 0; n < 4; n++){
    int d = n * 16 + l15;
    #pragma unroll
    for(int b4 = 0; b4 < 4; b4++){
      int srow = qt * 64 + w * 16 + l4 * 4 + b4;
      float val = accO[n][b4] / lrow[b4];
      o[(size_t)(b_ * 2048 + srow) * 1024 + h * 64 + d] = f2bf(val);
    }
  }
}

// ---------------- GEMM: C = A[M][K] * Bt[N][K]^T, bf16 in, f32 acc ----------
// EPI 0: Cf = acc + bias + resid      (wo: -> r1)
// EPI 1: Cb = bf16(gelu(acc + bias))  (w1: -> g)
// EPI 2: Cf = acc + bias + resid      (w2: -> r2)
template<int EPI>
__global__ __launch_bounds__(256) void gemm_bt(const u16* __restrict__ A,
                                               const u16* __restrict__ Bt,
                                               const float* __restrict__ bias,
                                               const float* __restrict__ resid,
                                               float* __restrict__ Cf,
                                               u16* __restrict__ Cb,
                                               int M, int N, int K){
  __shared__ u16 As[128 * 64];
  __shared__ u16 Bs[128 * 64];
  int tm = blockIdx.y, tn = blockIdx.x;
  int tid = threadIdx.x, lane = tid & 63, w = tid >> 6;
  int wr = (w >> 1) * 64, wc = (w & 1) * 64;
  int l15 = lane & 15, l4 = lane >> 4;
  f32x4 zero = {0.f, 0.f, 0.f, 0.f};
  f32x4 acc[4][4];
  #pragma unroll
  for(int m = 0; m < 4; m++)
    #pragma unroll
    for(int n = 0; n < 4; n++) acc[m][n] = zero;

  int r_st = tid >> 3;
  int c_st = (tid & 7) * 8;
  size_t abase = (size_t)tm * 128 * K;
  size_t bbase = (size_t)tn * 128 * K;

  for(int kt = 0; kt < K; kt += 64){
    __syncthreads();
    uint4 avv[4], bvv[4];
    #pragma unroll
    for(int p = 0; p < 4; p++){
      avv[p] = *(const uint4*)(A  + abase + (size_t)(r_st + p * 32) * K + kt + c_st);
      bvv[p] = *(const uint4*)(Bt + bbase + (size_t)(r_st + p * 32) * K + kt + c_st);
    }
    #pragma unroll
    for(int p = 0; p < 4; p++){
      *(uint4*)(As + (r_st + p * 32) * 64 + c_st) = avv[p];
      *(uint4*)(Bs + (r_st + p * 32) * 64 + c_st) = bvv[p];
    }
    __syncthreads();
    #pragma unroll
    for(int kc = 0; kc < 2; kc++){
      s16x8 af[4], bf[4];
      #pragma unroll
      for(int m = 0; m < 4; m++) af[m] = *(const s16x8*)(As + (wr + m * 16 + l15) * 64 + kc * 32 + l4 * 8);
      #pragma unroll
      for(int n = 0; n < 4; n++) bf[n] = *(const s16x8*)(Bs + (wc + n * 16 + l15) * 64 + kc * 32 + l4 * 8);
      #pragma unroll
      for(int m = 0; m < 4; m++)
        #pragma unroll
        for(int n = 0; n < 4; n++)
          acc[m][n] = mfma_bf16(af[m], bf[n], acc[m][n]);
    }
  }

  int row0 = tm * 128 + wr, col0 = tn * 128 + wc;
  #pragma unroll
  for(int n = 0; n < 4; n++){
    int col = col0 + n * 16 + l15;
    float bcol = bias[col];
    #pragma unroll
    for(int m = 0; m < 4; m++){
      #pragma unroll
      for(int b4 = 0; b4 < 4; b4++){
        int row = row0 + m * 16 + l4 * 4 + b4;
        size_t oi = (size_t)row * N + col;
        float vout = acc[m][n][b4] + bcol;
        if constexpr (EPI == 1){
          float gel = 0.5f * vout * (1.f + erff(vout * 0.70710678118f));
          Cb[oi] = f2bf(gel);
        } else {
          Cf[oi] = vout + resid[oi];
        }
      }
    }
  }
}

// ---------------- LayerNorm (row=1024), optional bf16 copy out --------------
__global__ __launch_bounds__(256) void ln_kernel(const float* __restrict__ a,
                                                 const float* __restrict__ w,
                                                 const float* __restrict__ bvec,
                                                 float* __restrict__ outf,
                                                 u16* __restrict__ outb,
                                                 int writeBf){
  int row = blockIdx.x;
  float4 val = ((const float4*)(a + (size_t)row * 1024))[threadIdx.x];
  float s  = val.x + val.y + val.z + val.w;
  float ss = val.x * val.x + val.y * val.y + val.z * val.z + val.w * val.w;
  #pragma unroll
  for(int off = 32; off > 0; off >>= 1){
    s  += __shfl_down(s, off);
    ss += __shfl_down(ss, off);
  }
  __shared__ float sb[8];
  int lane = threadIdx.x & 63, wv = threadIdx.x >> 6;
  if(lane == 0){ sb[wv] = s; sb[4 + wv] = ss; }
  __syncthreads();
  s  = sb[0] + sb[1] + sb[2] + sb[3];
  ss = sb[4] + sb[5] + sb[6] + sb[7];
  float mean = s * (1.f / 1024.f);
  float var  = ss * (1.f / 1024.f) - mean * mean;
  float rstd = rsqrtf(var + 1e-5f);
  int c = threadIdx.x * 4;
  float4 w4 = *(const float4*)(w + c);
  float4 b4 = *(const float4*)(bvec + c);
  float4 o4;
  o4.x = (val.x - mean) * rstd * w4.x + b4.x;
  o4.y = (val.y - mean) * rstd * w4.y + b4.y;
  o4.z = (val.z - mean) * rstd * w4.z + b4.z;
  o4.w = (val.w - mean) * rstd * w4.w + b4.w;
  ((float4*)(outf + (size_t)row * 1024))[threadIdx.x] = o4;
  if(writeBf){
    ushort4 ob = { f2bf(o4.x), f2bf(o4.y), f2bf(o4.z), f2bf(o4.w) };
    *(ushort4*)(outb + (size_t)row * 1024 + c) = ob;
  }
}

// ---------------------------------------------------------------------------
extern "C" void kernel_launch(void* const* d_in, const int* in_sizes, int n_in,
                              void* d_out, int out_size, void* d_ws, size_t ws_size,
                              hipStream_t stream){
  const float* x    = (const float*)d_in[0];
  const float* wq   = (const float*)d_in[1];
  const float* bq   = (const float*)d_in[2];
  const float* wk   = (const float*)d_in[3];
  const float* bk   = (const float*)d_in[4];
  const float* wv   = (const float*)d_in[5];
  const float* bv   = (const float*)d_in[6];
  const float* wo   = (const float*)d_in[7];
  const float* bo   = (const float*)d_in[8];
  const float* ln1w = (const float*)d_in[9];
  const float* ln1b = (const float*)d_in[10];
  const float* w1   = (const float*)d_in[11];
  const float* b1   = (const float*)d_in[12];
  const float* w2   = (const float*)d_in[13];
  const float* b2   = (const float*)d_in[14];
  const float* ln2w = (const float*)d_in[15];
  const float* ln2b = (const float*)d_in[16];
  float* out = (float*)d_out;

  char* ws8 = (char*)d_ws;
  u16*   qb  = (u16*)  (ws8 + ((size_t)0   << 20));  // 16 MiB  [B][H][S][64]
  u16*   kb  = (u16*)  (ws8 + ((size_t)16  << 20));  // 16 MiB
  u16*   vb  = (u16*)  (ws8 + ((size_t)32  << 20));  // 16 MiB
  u16*   ob  = (u16*)  (ws8 + ((size_t)48  << 20));  // 16 MiB  [B*S][1024]
  u16*   wot = (u16*)  (ws8 + ((size_t)64  << 20));  //  2 MiB  [1024][1024]
  u16*   w1t = (u16*)  (ws8 + ((size_t)66  << 20));  //  8 MiB  [4096][1024]
  u16*   w2t = (u16*)  (ws8 + ((size_t)74  << 20));  //  8 MiB  [1024][4096]
  u16*   tb  = (u16*)  (ws8 + ((size_t)82  << 20));  // 16 MiB  t bf16
  u16*   gb  = (u16*)  (ws8 + ((size_t)98  << 20));  // 64 MiB  g bf16 [8192][4096]
  float* rr  = (float*)(ws8 + ((size_t)162 << 20));  // 32 MiB  r1 then r2
  float* tf  = (float*)(ws8 + ((size_t)194 << 20));  // 32 MiB  t f32
  // total 226 MiB

  transpose_cast<<<dim3(32, 32),  256, 0, stream>>>(wo, wot, 1024, 1024);
  transpose_cast<<<dim3(128, 32), 256, 0, stream>>>(w1, w1t, 1024, 4096);
  transpose_cast<<<dim3(32, 128), 256, 0, stream>>>(w2, w2t, 4096, 1024);

  qkv_kernel<<<dim3(256, 16), 256, 0, stream>>>(x, wq, bq, wk, bk, wv, bv, qb, kb, vb);
  attn_kernel<<<dim3(32, 64), 256, 0, stream>>>(qb, kb, vb, ob);

  // r1 = o @ wo + bo + x
  gemm_bt<0><<<dim3(8, 64), 256, 0, stream>>>(ob, wot, bo, x, rr, nullptr, 8192, 1024, 1024);
  // t = LN1(r1)  (f32 + bf16)
  ln_kernel<<<dim3(8192), 256, 0, stream>>>(rr, ln1w, ln1b, tf, tb, 1);
  // g = gelu(t @ w1 + b1)
  gemm_bt<1><<<dim3(32, 64), 256, 0, stream>>>(tb, w1t, b1, nullptr, nullptr, gb, 8192, 4096, 1024);
  // r2 = g @ w2 + b2 + t
  gemm_bt<2><<<dim3(8, 64), 256, 0, stream>>>(gb, w2t, b2, tf, rr, nullptr, 8192, 1024, 4096);
  // out = LN2(r2)
  ln_kernel<<<dim3(8192), 256, 0, stream>>>(rr, ln2w, ln2b, out, nullptr, 0);
}

// Round 2
// 513.426 us; speedup vs baseline: 1.6233x; 1.6233x over previous
//
#include <hip/hip_runtime.h>

typedef unsigned short u16;
typedef unsigned int u32;
typedef float f32x4 __attribute__((ext_vector_type(4)));
typedef short s16x8 __attribute__((ext_vector_type(8)));
typedef u32 u32x4 __attribute__((ext_vector_type(4)));

#define DEV static __device__ __forceinline__

DEV u16 f2bf(float f){
  unsigned u = __float_as_uint(f);
  u += 0x7fffu + ((u>>16)&1u);
  return (u16)(u>>16);
}

DEV u32 cvt_pk_bf16(float lo, float hi){
  u32 r;
  asm("v_cvt_pk_bf16_f32 %0, %1, %2" : "=v"(r) : "v"(lo), "v"(hi));
  return r;
}

DEV f32x4 mfma_bf16(s16x8 a, s16x8 b, f32x4 c){
  return __builtin_amdgcn_mfma_f32_16x16x32_bf16(a, b, c, 0, 0, 0);
}

DEV void gll16(const void* g, void* l){
  __builtin_amdgcn_global_load_lds((const __attribute__((address_space(1))) u32*)g,
                                   (__attribute__((address_space(3))) u32*)l, 16, 0, 0);
}

// ---------------- transpose + cast: w [K][N] f32 -> wt [N][K] bf16 ----------
__global__ __launch_bounds__(256) void transpose_cast(const float* __restrict__ w,
                                                      u16* __restrict__ wt,
                                                      int K, int N){
  __shared__ float tile[32][33];
  int n0 = blockIdx.x * 32, k0 = blockIdx.y * 32;
  int tx = threadIdx.x & 31, ty = threadIdx.x >> 5;   // 32 x 8
  #pragma unroll
  for(int j = 0; j < 32; j += 8)
    tile[ty + j][tx] = w[(size_t)(k0 + ty + j) * N + n0 + tx];
  __syncthreads();
  #pragma unroll
  for(int j = 0; j < 32; j += 8)
    wt[(size_t)(n0 + ty + j) * K + k0 + tx] = f2bf(tile[tx][ty + j]);
}

// ---------------- QKV projection (per-head 64x64, shared weights) -----------
// x [B*S][1024] f32 -> q/k [B][H][S][64] bf16, v -> V^T [B][H][64][S] bf16
__global__ __launch_bounds__(256) void qkv_kernel(const float* __restrict__ x,
    const float* __restrict__ wq, const float* __restrict__ bq,
    const float* __restrict__ wk, const float* __restrict__ bk,
    const float* __restrict__ wv, const float* __restrict__ bv,
    u16* __restrict__ qo, u16* __restrict__ ko, u16* __restrict__ vo){
  __shared__ float ws[3 * 64 * 64];   // 48 KiB
  __shared__ float xs[32 * 64];       // 8 KiB
  int h  = blockIdx.y;
  int r0 = blockIdx.x * 32;           // global row base (over B*S)
  for(int i = threadIdx.x; i < 1024; i += 256) ((float4*)ws)[i]        = ((const float4*)wq)[i];
  for(int i = threadIdx.x; i < 1024; i += 256) ((float4*)ws)[1024 + i] = ((const float4*)wk)[i];
  for(int i = threadIdx.x; i < 1024; i += 256) ((float4*)ws)[2048 + i] = ((const float4*)wv)[i];
  for(int i = threadIdx.x; i < 512; i += 256){
    int r = i >> 4, c4 = (i & 15) * 4;
    ((float4*)xs)[i] = *(const float4*)(x + (size_t)(r0 + r) * 1024 + h * 64 + c4);
  }
  __syncthreads();
  int r  = threadIdx.x >> 3;
  int j0 = (threadIdx.x & 7) * 8;
  float aq[8], ak[8], av[8];
  #pragma unroll
  for(int j = 0; j < 8; j++){ aq[j] = 0.f; ak[j] = 0.f; av[j] = 0.f; }
  for(int i = 0; i < 64; i++){
    float xv = xs[r * 64 + i];
    const float* wr = ws + i * 64 + j0;
    #pragma unroll
    for(int j = 0; j < 8; j++){
      aq[j] = fmaf(xv, wr[j],        aq[j]);
      ak[j] = fmaf(xv, wr[4096 + j], ak[j]);
      av[j] = fmaf(xv, wr[8192 + j], av[j]);
    }
  }
  int g = r0 + r, b = g >> 11, s = g & 2047;
  int bh = b * 16 + h;
  size_t base = ((size_t)bh * 2048 + s) * 64 + j0;
  ushort4 q_lo = { f2bf(aq[0]+bq[j0+0]), f2bf(aq[1]+bq[j0+1]), f2bf(aq[2]+bq[j0+2]), f2bf(aq[3]+bq[j0+3]) };
  ushort4 q_hi = { f2bf(aq[4]+bq[j0+4]), f2bf(aq[5]+bq[j0+5]), f2bf(aq[6]+bq[j0+6]), f2bf(aq[7]+bq[j0+7]) };
  ushort4 k_lo = { f2bf(ak[0]+bk[j0+0]), f2bf(ak[1]+bk[j0+1]), f2bf(ak[2]+bk[j0+2]), f2bf(ak[3]+bk[j0+3]) };
  ushort4 k_hi = { f2bf(ak[4]+bk[j0+4]), f2bf(ak[5]+bk[j0+5]), f2bf(ak[6]+bk[j0+6]), f2bf(ak[7]+bk[j0+7]) };
  *(ushort4*)(qo + base)     = q_lo;  *(ushort4*)(qo + base + 4) = q_hi;
  *(ushort4*)(ko + base)     = k_lo;  *(ushort4*)(ko + base + 4) = k_hi;
  // V^T scatter: vo[bh][d][s]
  size_t vtb = (size_t)bh * 64 * 2048 + s;
  #pragma unroll
  for(int j = 0; j < 8; j++)
    vo[vtb + (size_t)(j0 + j) * 2048] = f2bf(av[j] + bv[j0 + j]);
}

// ---------------- flash attention, causal, swapped-operand, LDS-free --------
// q/k [bh][2048][64] bf16, vT [bh][64][2048] bf16 -> o [B*S][1024] bf16
__global__ __launch_bounds__(256) void attn_kernel(const u16* __restrict__ q,
                                                   const u16* __restrict__ k,
                                                   const u16* __restrict__ vT,
                                                   u16* __restrict__ o){
  int task = blockIdx.x * 4 + (threadIdx.x >> 6);
  int qt = 31 - (task >> 6);        // heavy tiles dispatched first
  int bh = task & 63;               // same-bh tasks land on same XCD (stride 16 blocks)
  int lane = threadIdx.x & 63;
  int l15 = lane & 15, l4 = lane >> 4;
  size_t kvbase = (size_t)bh * 2048 * 64;
  size_t vtbase = (size_t)bh * 64 * 2048;

  // Q frags (B-operand: row = q = l15, cols d = kc*32 + l4*8 .. +7)
  s16x8 qf[4][2];
  #pragma unroll
  for(int nq = 0; nq < 4; nq++)
    #pragma unroll
    for(int kc = 0; kc < 2; kc++)
      qf[nq][kc] = *(const s16x8*)(q + kvbase + (size_t)(qt*64 + nq*16 + l15) * 64 + kc*32 + l4*8);

  f32x4 zero = {0.f, 0.f, 0.f, 0.f};
  f32x4 accO[4][4];                 // [md][nq] : O^T, row d = md*16+l4*4+b, col q = nq*16+l15
  #pragma unroll
  for(int md = 0; md < 4; md++)
    #pragma unroll
    for(int nq = 0; nq < 4; nq++) accO[md][nq] = zero;
  float mrow[4], lrow[4];
  #pragma unroll
  for(int nq = 0; nq < 4; nq++){ mrow[nq] = -3.0e38f; lrow[nq] = 0.f; }

  int srcA = l15 + ((l4 & 1) << 5);
  int srcB = srcA + 16;
  bool up  = (l4 >> 1) != 0;

  for(int kt = 0; kt <= qt; kt++){
    s16x8 kf[4][2], vf[4][2];
    #pragma unroll
    for(int mk = 0; mk < 4; mk++)
      #pragma unroll
      for(int kc = 0; kc < 2; kc++)
        kf[mk][kc] = *(const s16x8*)(k + kvbase + (size_t)(kt*64 + mk*16 + l15)*64 + kc*32 + l4*8);
    #pragma unroll
    for(int md = 0; md < 4; md++)
      #pragma unroll
      for(int kc = 0; kc < 2; kc++)
        vf[md][kc] = *(const s16x8*)(vT + vtbase + (size_t)(md*16 + l15)*2048 + kt*64 + kc*32 + l4*8);

    #pragma unroll
    for(int nq = 0; nq < 4; nq++){
      // S^T = mfma(K, Q): row k = mk*16+l4*4+b, col q = nq*16+l15
      f32x4 sc[4];
      #pragma unroll
      for(int mk = 0; mk < 4; mk++){
        f32x4 a = zero;
        a = mfma_bf16(kf[mk][0], qf[nq][0], a);
        a = mfma_bf16(kf[mk][1], qf[nq][1], a);
        sc[mk] = a * 0.125f;
      }
      if(kt == qt){
        int ql = nq*16 + l15;
        #pragma unroll
        for(int mk = 0; mk < 4; mk++){
          int kl = mk*16 + l4*4;
          #pragma unroll
          for(int b = 0; b < 4; b++)
            if(kl + b > ql) sc[mk][b] = -3.0e38f;
        }
      }
      // online softmax: row q is lane-local; reduce over l4 group only
      float lm = sc[0][0];
      #pragma unroll
      for(int mk = 0; mk < 4; mk++)
        #pragma unroll
        for(int b = 0; b < 4; b++) lm = fmaxf(lm, sc[mk][b]);
      lm = fmaxf(lm, __shfl_xor(lm, 16));
      lm = fmaxf(lm, __shfl_xor(lm, 32));
      float mnew  = fmaxf(mrow[nq], lm);
      float alpha = __expf(mrow[nq] - mnew);
      mrow[nq] = mnew;
      float rs = 0.f;
      #pragma unroll
      for(int mk = 0; mk < 4; mk++)
        #pragma unroll
        for(int b = 0; b < 4; b++){
          sc[mk][b] = __expf(sc[mk][b] - mnew);
          rs += sc[mk][b];
        }
      rs += __shfl_xor(rs, 16);
      rs += __shfl_xor(rs, 32);
      lrow[nq] = lrow[nq] * alpha + rs;
      #pragma unroll
      for(int md = 0; md < 4; md++) accO[md][nq] *= alpha;

      // pack P^T -> bf16 pairs, then shuffle into B-frag (row q, k-contig)
      u32 plo[4], phi[4];
      #pragma unroll
      for(int mk = 0; mk < 4; mk++){
        plo[mk] = cvt_pk_bf16(sc[mk][0], sc[mk][1]);
        phi[mk] = cvt_pk_bf16(sc[mk][2], sc[mk][3]);
      }
      #pragma unroll
      for(int kc = 0; kc < 2; kc++){
        u32 lo0a = (u32)__shfl((int)plo[2*kc],   srcA);
        u32 hi0a = (u32)__shfl((int)phi[2*kc],   srcA);
        u32 lo1a = (u32)__shfl((int)plo[2*kc+1], srcA);
        u32 hi1a = (u32)__shfl((int)phi[2*kc+1], srcA);
        u32 lo0b = (u32)__shfl((int)plo[2*kc],   srcB);
        u32 hi0b = (u32)__shfl((int)phi[2*kc],   srcB);
        u32 lo1b = (u32)__shfl((int)plo[2*kc+1], srcB);
        u32 hi1b = (u32)__shfl((int)phi[2*kc+1], srcB);
        union { u32x4 u; s16x8 h; } pb;
        pb.u[0] = up ? lo1a : lo0a;
        pb.u[1] = up ? hi1a : hi0a;
        pb.u[2] = up ? lo1b : lo0b;
        pb.u[3] = up ? hi1b : hi0b;
        #pragma unroll
        for(int md = 0; md < 4; md++)
          accO[md][nq] = mfma_bf16(vf[md][kc], pb.h, accO[md][nq]);
      }
    }
  }
  // epilogue: O = accO^T / l
  int b_ = bh >> 4, h = bh & 15;
  #pragma unroll
  for(int nq = 0; nq < 4; nq++){
    float inv = 1.f / lrow[nq];
    int qrow = qt*64 + nq*16 + l15;
    #pragma unroll
    for(int md = 0; md < 4; md++){
      int d0 = md*16 + l4*4;
      ushort4 ov;
      ov.x = f2bf(accO[md][nq][0] * inv);
      ov.y = f2bf(accO[md][nq][1] * inv);
      ov.z = f2bf(accO[md][nq][2] * inv);
      ov.w = f2bf(accO[md][nq][3] * inv);
      *(ushort4*)(o + ((size_t)(b_*2048 + qrow))*1024 + h*64 + d0) = ov;
    }
  }
}

// ---------------- GEMM: C = A[M][K] * Bt[N][K]^T, bf16 in, f32 acc ----------
// EPI 0/2: Cf = acc + bias + resid      (wo -> r1, w2 -> r2)
// EPI 1:   Cb = bf16(gelu(acc + bias))  (w1 -> g)
template<int EPI>
__global__ __launch_bounds__(256) void gemm_bt(const u16* __restrict__ A,
                                               const u16* __restrict__ Bt,
                                               const float* __restrict__ bias,
                                               const float* __restrict__ resid,
                                               float* __restrict__ Cf,
                                               u16* __restrict__ Cb,
                                               int M, int N, int K){
  __shared__ u16 As[128 * 64];
  __shared__ u16 Bs[128 * 64];
  int tm = blockIdx.y, tn = blockIdx.x;
  int tid = threadIdx.x, lane = tid & 63, w = tid >> 6;
  int wr = (w >> 1) * 64, wc = (w & 1) * 64;
  int l15 = lane & 15, l4 = lane >> 4;
  f32x4 zero = {0.f, 0.f, 0.f, 0.f};
  f32x4 acc[4][4];
  #pragma unroll
  for(int m = 0; m < 4; m++)
    #pragma unroll
    for(int n = 0; n < 4; n++) acc[m][n] = zero;

  // lane-linear LDS staging for global_load_lds: byte off = w*1024 + lane*16
  int srow = w * 8 + (lane >> 3);
  int scol = (lane & 7) * 8;
  size_t abase = (size_t)tm * 128 * K;
  size_t bbase = (size_t)tn * 128 * K;
  const u16* Ag = A  + abase + (size_t)srow * K + scol;
  const u16* Bg = Bt + bbase + (size_t)srow * K + scol;
  u16* Al = As + srow * 64 + scol;
  u16* Bl = Bs + srow * 64 + scol;

  for(int kt = 0; kt < K; kt += 64){
    __syncthreads();
    #pragma unroll
    for(int p = 0; p < 4; p++){
      gll16(Ag + (size_t)p * 32 * K + kt, Al + p * 32 * 64);
      gll16(Bg + (size_t)p * 32 * K + kt, Bl + p * 32 * 64);
    }
    __syncthreads();
    #pragma unroll
    for(int kc = 0; kc < 2; kc++){
      s16x8 af[4], bf[4];
      #pragma unroll
      for(int m = 0; m < 4; m++) af[m] = *(const s16x8*)(As + (wr + m * 16 + l15) * 64 + kc * 32 + l4 * 8);
      #pragma unroll
      for(int n = 0; n < 4; n++) bf[n] = *(const s16x8*)(Bs + (wc + n * 16 + l15) * 64 + kc * 32 + l4 * 8);
      #pragma unroll
      for(int m = 0; m < 4; m++)
        #pragma unroll
        for(int n = 0; n < 4; n++)
          acc[m][n] = mfma_bf16(af[m], bf[n], acc[m][n]);
    }
  }

  int row0 = tm * 128 + wr, col0 = tn * 128 + wc;
  #pragma unroll
  for(int n = 0; n < 4; n++){
    int col = col0 + n * 16 + l15;
    float bcol = bias[col];
    #pragma unroll
    for(int m = 0; m < 4; m++){
      #pragma unroll
      for(int b4 = 0; b4 < 4; b4++){
        int row = row0 + m * 16 + l4 * 4 + b4;
        size_t oi = (size_t)row * N + col;
        float vout = acc[m][n][b4] + bcol;
        if constexpr (EPI == 1){
          float gel = 0.5f * vout * (1.f + erff(vout * 0.70710678118f));
          Cb[oi] = f2bf(gel);
        } else {
          Cf[oi] = vout + resid[oi];
        }
      }
    }
  }
}

// ---------------- LayerNorm (row=1024), optional bf16 copy out --------------
__global__ __launch_bounds__(256) void ln_kernel(const float* __restrict__ a,
                                                 const float* __restrict__ w,
                                                 const float* __restrict__ bvec,
                                                 float* __restrict__ outf,
                                                 u16* __restrict__ outb,
                                                 int writeBf){
  int row = blockIdx.x;
  float4 val = ((const float4*)(a + (size_t)row * 1024))[threadIdx.x];
  float s  = val.x + val.y + val.z + val.w;
  float ss = val.x * val.x + val.y * val.y + val.z * val.z + val.w * val.w;
  #pragma unroll
  for(int off = 32; off > 0; off >>= 1){
    s  += __shfl_down(s, off);
    ss += __shfl_down(ss, off);
  }
  __shared__ float sb[8];
  int lane = threadIdx.x & 63, wv = threadIdx.x >> 6;
  if(lane == 0){ sb[wv] = s; sb[4 + wv] = ss; }
  __syncthreads();
  s  = sb[0] + sb[1] + sb[2] + sb[3];
  ss = sb[4] + sb[5] + sb[6] + sb[7];
  float mean = s * (1.f / 1024.f);
  float var  = ss * (1.f / 1024.f) - mean * mean;
  float rstd = rsqrtf(var + 1e-5f);
  int c = threadIdx.x * 4;
  float4 w4 = *(const float4*)(w + c);
  float4 b4 = *(const float4*)(bvec + c);
  float4 o4;
  o4.x = (val.x - mean) * rstd * w4.x + b4.x;
  o4.y = (val.y - mean) * rstd * w4.y + b4.y;
  o4.z = (val.z - mean) * rstd * w4.z + b4.z;
  o4.w = (val.w - mean) * rstd * w4.w + b4.w;
  ((float4*)(outf + (size_t)row * 1024))[threadIdx.x] = o4;
  if(writeBf){
    ushort4 ob = { f2bf(o4.x), f2bf(o4.y), f2bf(o4.z), f2bf(o4.w) };
    *(ushort4*)(outb + (size_t)row * 1024 + c) = ob;
  }
}

// ---------------------------------------------------------------------------
extern "C" void kernel_launch(void* const* d_in, const int* in_sizes, int n_in,
                              void* d_out, int out_size, void* d_ws, size_t ws_size,
                              hipStream_t stream){
  const float* x    = (const float*)d_in[0];
  const float* wq   = (const float*)d_in[1];
  const float* bq   = (const float*)d_in[2];
  const float* wk   = (const float*)d_in[3];
  const float* bk   = (const float*)d_in[4];
  const float* wv   = (const float*)d_in[5];
  const float* bv   = (const float*)d_in[6];
  const float* wo   = (const float*)d_in[7];
  const float* bo   = (const float*)d_in[8];
  const float* ln1w = (const float*)d_in[9];
  const float* ln1b = (const float*)d_in[10];
  const float* w1   = (const float*)d_in[11];
  const float* b1   = (const float*)d_in[12];
  const float* w2   = (const float*)d_in[13];
  const float* b2   = (const float*)d_in[14];
  const float* ln2w = (const float*)d_in[15];
  const float* ln2b = (const float*)d_in[16];
  float* out = (float*)d_out;

  char* ws8 = (char*)d_ws;
  u16*   qb  = (u16*)  (ws8 + ((size_t)0   << 20));  // 16 MiB  [B][H][S][64]
  u16*   kb  = (u16*)  (ws8 + ((size_t)16  << 20));  // 16 MiB
  u16*   vb  = (u16*)  (ws8 + ((size_t)32  << 20));  // 16 MiB  V^T [B][H][64][S]
  u16*   ob  = (u16*)  (ws8 + ((size_t)48  << 20));  // 16 MiB  [B*S][1024]
  u16*   wot = (u16*)  (ws8 + ((size_t)64  << 20));  //  2 MiB  [1024][1024]
  u16*   w1t = (u16*)  (ws8 + ((size_t)66  << 20));  //  8 MiB  [4096][1024]
  u16*   w2t = (u16*)  (ws8 + ((size_t)74  << 20));  //  8 MiB  [1024][4096]
  u16*   tb  = (u16*)  (ws8 + ((size_t)82  << 20));  // 16 MiB  t bf16
  u16*   gb  = (u16*)  (ws8 + ((size_t)98  << 20));  // 64 MiB  g bf16 [8192][4096]
  float* rr  = (float*)(ws8 + ((size_t)162 << 20));  // 32 MiB  r1 then r2
  float* tf  = (float*)(ws8 + ((size_t)194 << 20));  // 32 MiB  t f32

  transpose_cast<<<dim3(32, 32),  256, 0, stream>>>(wo, wot, 1024, 1024);
  transpose_cast<<<dim3(128, 32), 256, 0, stream>>>(w1, w1t, 1024, 4096);
  transpose_cast<<<dim3(32, 128), 256, 0, stream>>>(w2, w2t, 4096, 1024);

  qkv_kernel<<<dim3(256, 16), 256, 0, stream>>>(x, wq, bq, wk, bk, wv, bv, qb, kb, vb);
  attn_kernel<<<dim3(512), 256, 0, stream>>>(qb, kb, vb, ob);

  // r1 = o @ wo + bo + x
  gemm_bt<0><<<dim3(8, 64), 256, 0, stream>>>(ob, wot, bo, x, rr, nullptr, 8192, 1024, 1024);
  // t = LN1(r1)  (f32 + bf16)
  ln_kernel<<<dim3(8192), 256, 0, stream>>>(rr, ln1w, ln1b, tf, tb, 1);
  // g = gelu(t @ w1 + b1)
  gemm_bt<1><<<dim3(32, 64), 256, 0, stream>>>(tb, w1t, b1, nullptr, nullptr, gb, 8192, 4096, 1024);
  // r2 = g @ w2 + b2 + t
  gemm_bt<2><<<dim3(8, 64), 256, 0, stream>>>(gb, w2t, b2, tf, rr, nullptr, 8192, 1024, 4096);
  // out = LN2(r2)
  ln_kernel<<<dim3(8192), 256, 0, stream>>>(rr, ln2w, ln2b, out, nullptr, 0);
}

// Round 3
// 435.031 us; speedup vs baseline: 1.9159x; 1.1802x over previous
//
#include <hip/hip_runtime.h>

typedef unsigned short u16;
typedef unsigned int u32;
typedef float f32x4 __attribute__((ext_vector_type(4)));
typedef short s16x8 __attribute__((ext_vector_type(8)));
typedef u32 u32x4 __attribute__((ext_vector_type(4)));

#define DEV static __device__ __forceinline__

DEV u16 f2bf(float f){
  unsigned u = __float_as_uint(f);
  u += 0x7fffu + ((u>>16)&1u);
  return (u16)(u>>16);
}

DEV u32 cvt_pk_bf16(float lo, float hi){
  u32 r;
  asm("v_cvt_pk_bf16_f32 %0, %1, %2" : "=v"(r) : "v"(lo), "v"(hi));
  return r;
}

DEV f32x4 mfma_bf16(s16x8 a, s16x8 b, f32x4 c){
  return __builtin_amdgcn_mfma_f32_16x16x32_bf16(a, b, c, 0, 0, 0);
}

DEV void gll16(const void* g, void* l){
  __builtin_amdgcn_global_load_lds((const __attribute__((address_space(1))) u32*)g,
                                   (__attribute__((address_space(3))) u32*)l, 16, 0, 0);
}

// ---------------- transpose + cast: w [K][N] f32 -> wt [N][K] bf16 ----------
__global__ __launch_bounds__(256) void transpose_cast(const float* __restrict__ w,
                                                      u16* __restrict__ wt,
                                                      int K, int N){
  __shared__ float tile[32][33];
  int n0 = blockIdx.x * 32, k0 = blockIdx.y * 32;
  int tx = threadIdx.x & 31, ty = threadIdx.x >> 5;   // 32 x 8
  #pragma unroll
  for(int j = 0; j < 32; j += 8)
    tile[ty + j][tx] = w[(size_t)(k0 + ty + j) * N + n0 + tx];
  __syncthreads();
  #pragma unroll
  for(int j = 0; j < 32; j += 8)
    wt[(size_t)(n0 + ty + j) * K + k0 + tx] = f2bf(tile[tx][ty + j]);
}

// ---------------- QKV projection (per-head 64x64, shared weights) -----------
// x [B*S][1024] f32 -> q/k [B][H][S][64] bf16, v -> V^T [B][H][64][S] bf16
__global__ __launch_bounds__(256) void qkv_kernel(const float* __restrict__ x,
    const float* __restrict__ wq, const float* __restrict__ bq,
    const float* __restrict__ wk, const float* __restrict__ bk,
    const float* __restrict__ wv, const float* __restrict__ bv,
    u16* __restrict__ qo, u16* __restrict__ ko, u16* __restrict__ vo){
  __shared__ float ws[3 * 64 * 64];   // 48 KiB
  __shared__ float xs[32 * 64];       // 8 KiB
  int h  = blockIdx.y;
  int r0 = blockIdx.x * 32;           // global row base (over B*S)
  for(int i = threadIdx.x; i < 1024; i += 256) ((float4*)ws)[i]        = ((const float4*)wq)[i];
  for(int i = threadIdx.x; i < 1024; i += 256) ((float4*)ws)[1024 + i] = ((const float4*)wk)[i];
  for(int i = threadIdx.x; i < 1024; i += 256) ((float4*)ws)[2048 + i] = ((const float4*)wv)[i];
  for(int i = threadIdx.x; i < 512; i += 256){
    int r = i >> 4, c4 = (i & 15) * 4;
    ((float4*)xs)[i] = *(const float4*)(x + (size_t)(r0 + r) * 1024 + h * 64 + c4);
  }
  __syncthreads();
  int r  = threadIdx.x >> 3;
  int j0 = (threadIdx.x & 7) * 8;
  float aq[8], ak[8], av[8];
  #pragma unroll
  for(int j = 0; j < 8; j++){ aq[j] = 0.f; ak[j] = 0.f; av[j] = 0.f; }
  for(int i = 0; i < 64; i++){
    float xv = xs[r * 64 + i];
    const float* wr = ws + i * 64 + j0;
    #pragma unroll
    for(int j = 0; j < 8; j++){
      aq[j] = fmaf(xv, wr[j],        aq[j]);
      ak[j] = fmaf(xv, wr[4096 + j], ak[j]);
      av[j] = fmaf(xv, wr[8192 + j], av[j]);
    }
  }
  int g = r0 + r, b = g >> 11, s = g & 2047;
  int bh = b * 16 + h;
  size_t base = ((size_t)bh * 2048 + s) * 64 + j0;
  ushort4 q_lo = { f2bf(aq[0]+bq[j0+0]), f2bf(aq[1]+bq[j0+1]), f2bf(aq[2]+bq[j0+2]), f2bf(aq[3]+bq[j0+3]) };
  ushort4 q_hi = { f2bf(aq[4]+bq[j0+4]), f2bf(aq[5]+bq[j0+5]), f2bf(aq[6]+bq[j0+6]), f2bf(aq[7]+bq[j0+7]) };
  ushort4 k_lo = { f2bf(ak[0]+bk[j0+0]), f2bf(ak[1]+bk[j0+1]), f2bf(ak[2]+bk[j0+2]), f2bf(ak[3]+bk[j0+3]) };
  ushort4 k_hi = { f2bf(ak[4]+bk[j0+4]), f2bf(ak[5]+bk[j0+5]), f2bf(ak[6]+bk[j0+6]), f2bf(ak[7]+bk[j0+7]) };
  *(ushort4*)(qo + base)     = q_lo;  *(ushort4*)(qo + base + 4) = q_hi;
  *(ushort4*)(ko + base)     = k_lo;  *(ushort4*)(ko + base + 4) = k_hi;
  // V^T scatter: vo[bh][d][s]
  size_t vtb = (size_t)bh * 64 * 2048 + s;
  #pragma unroll
  for(int j = 0; j < 8; j++)
    vo[vtb + (size_t)(j0 + j) * 2048] = f2bf(av[j] + bv[j0 + j]);
}

// ---------------- flash attention, causal, swapped-operand, LDS-free --------
__global__ __launch_bounds__(256) void attn_kernel(const u16* __restrict__ q,
                                                   const u16* __restrict__ k,
                                                   const u16* __restrict__ vT,
                                                   u16* __restrict__ o){
  int task = blockIdx.x * 4 + (threadIdx.x >> 6);
  int qt = 31 - (task >> 6);        // heavy tiles dispatched first
  int bh = task & 63;
  int lane = threadIdx.x & 63;
  int l15 = lane & 15, l4 = lane >> 4;
  size_t kvbase = (size_t)bh * 2048 * 64;
  size_t vtbase = (size_t)bh * 64 * 2048;

  s16x8 qf[4][2];
  #pragma unroll
  for(int nq = 0; nq < 4; nq++)
    #pragma unroll
    for(int kc = 0; kc < 2; kc++)
      qf[nq][kc] = *(const s16x8*)(q + kvbase + (size_t)(qt*64 + nq*16 + l15) * 64 + kc*32 + l4*8);

  f32x4 zero = {0.f, 0.f, 0.f, 0.f};
  f32x4 accO[4][4];
  #pragma unroll
  for(int md = 0; md < 4; md++)
    #pragma unroll
    for(int nq = 0; nq < 4; nq++) accO[md][nq] = zero;
  float mrow[4], lrow[4];
  #pragma unroll
  for(int nq = 0; nq < 4; nq++){ mrow[nq] = -3.0e38f; lrow[nq] = 0.f; }

  int srcA = l15 + ((l4 & 1) << 5);
  int srcB = srcA + 16;
  bool up  = (l4 >> 1) != 0;

  for(int kt = 0; kt <= qt; kt++){
    s16x8 kf[4][2], vf[4][2];
    #pragma unroll
    for(int mk = 0; mk < 4; mk++)
      #pragma unroll
      for(int kc = 0; kc < 2; kc++)
        kf[mk][kc] = *(const s16x8*)(k + kvbase + (size_t)(kt*64 + mk*16 + l15)*64 + kc*32 + l4*8);
    #pragma unroll
    for(int md = 0; md < 4; md++)
      #pragma unroll
      for(int kc = 0; kc < 2; kc++)
        vf[md][kc] = *(const s16x8*)(vT + vtbase + (size_t)(md*16 + l15)*2048 + kt*64 + kc*32 + l4*8);

    #pragma unroll
    for(int nq = 0; nq < 4; nq++){
      f32x4 sc[4];
      #pragma unroll
      for(int mk = 0; mk < 4; mk++){
        f32x4 a = zero;
        a = mfma_bf16(kf[mk][0], qf[nq][0], a);
        a = mfma_bf16(kf[mk][1], qf[nq][1], a);
        sc[mk] = a * 0.125f;
      }
      if(kt == qt){
        int ql = nq*16 + l15;
        #pragma unroll
        for(int mk = 0; mk < 4; mk++){
          int kl = mk*16 + l4*4;
          #pragma unroll
          for(int b = 0; b < 4; b++)
            if(kl + b > ql) sc[mk][b] = -3.0e38f;
        }
      }
      float lm = sc[0][0];
      #pragma unroll
      for(int mk = 0; mk < 4; mk++)
        #pragma unroll
        for(int b = 0; b < 4; b++) lm = fmaxf(lm, sc[mk][b]);
      lm = fmaxf(lm, __shfl_xor(lm, 16));
      lm = fmaxf(lm, __shfl_xor(lm, 32));
      float mnew  = fmaxf(mrow[nq], lm);
      float alpha = __expf(mrow[nq] - mnew);
      mrow[nq] = mnew;
      float rs = 0.f;
      #pragma unroll
      for(int mk = 0; mk < 4; mk++)
        #pragma unroll
        for(int b = 0; b < 4; b++){
          sc[mk][b] = __expf(sc[mk][b] - mnew);
          rs += sc[mk][b];
        }
      rs += __shfl_xor(rs, 16);
      rs += __shfl_xor(rs, 32);
      lrow[nq] = lrow[nq] * alpha + rs;
      #pragma unroll
      for(int md = 0; md < 4; md++) accO[md][nq] *= alpha;

      u32 plo[4], phi[4];
      #pragma unroll
      for(int mk = 0; mk < 4; mk++){
        plo[mk] = cvt_pk_bf16(sc[mk][0], sc[mk][1]);
        phi[mk] = cvt_pk_bf16(sc[mk][2], sc[mk][3]);
      }
      #pragma unroll
      for(int kc = 0; kc < 2; kc++){
        u32 lo0a = (u32)__shfl((int)plo[2*kc],   srcA);
        u32 hi0a = (u32)__shfl((int)phi[2*kc],   srcA);
        u32 lo1a = (u32)__shfl((int)plo[2*kc+1], srcA);
        u32 hi1a = (u32)__shfl((int)phi[2*kc+1], srcA);
        u32 lo0b = (u32)__shfl((int)plo[2*kc],   srcB);
        u32 hi0b = (u32)__shfl((int)phi[2*kc],   srcB);
        u32 lo1b = (u32)__shfl((int)plo[2*kc+1], srcB);
        u32 hi1b = (u32)__shfl((int)phi[2*kc+1], srcB);
        union { u32x4 u; s16x8 h; } pb;
        pb.u[0] = up ? lo1a : lo0a;
        pb.u[1] = up ? hi1a : hi0a;
        pb.u[2] = up ? lo1b : lo0b;
        pb.u[3] = up ? hi1b : hi0b;
        #pragma unroll
        for(int md = 0; md < 4; md++)
          accO[md][nq] = mfma_bf16(vf[md][kc], pb.h, accO[md][nq]);
      }
    }
  }
  int b_ = bh >> 4, h = bh & 15;
  #pragma unroll
  for(int nq = 0; nq < 4; nq++){
    float inv = 1.f / lrow[nq];
    int qrow = qt*64 + nq*16 + l15;
    #pragma unroll
    for(int md = 0; md < 4; md++){
      int d0 = md*16 + l4*4;
      ushort4 ov;
      ov.x = f2bf(accO[md][nq][0] * inv);
      ov.y = f2bf(accO[md][nq][1] * inv);
      ov.z = f2bf(accO[md][nq][2] * inv);
      ov.w = f2bf(accO[md][nq][3] * inv);
      *(ushort4*)(o + ((size_t)(b_*2048 + qrow))*1024 + h*64 + d0) = ov;
    }
  }
}

// ---------------- 2-phase double-buffered GEMM: C = A * Bt^T ----------------
// EPI 0/2: Cf = acc + bias + resid ; EPI 1: Cb = bf16(gelu(acc + bias))
template<int EPI, int BM, int BN, int WM, int WN>
__global__ __launch_bounds__(WM*WN*64) void gemm_dbuf(const u16* __restrict__ A,
    const u16* __restrict__ Bt, const float* __restrict__ bias,
    const float* __restrict__ resid, float* __restrict__ Cf, u16* __restrict__ Cb,
    int M, int N, int K, int ntn){
  constexpr int THREADS = WM*WN*64;
  constexpr int RM = BM/(WM*16), RN = BN/(WN*16);
  constexpr int LDSH = (BM+BN)*64;          // u16 elems per buffer
  constexpr int RSTEP = THREADS/8;          // rows per staging pass
  constexpr int PA = BM/RSTEP, PB = BN/RSTEP;
  __shared__ u16 lds[2*LDSH];

  // bijective XCD swizzle (nwg % 8 == 0 by construction)
  int nwg = gridDim.x;
  int cq = nwg >> 3;
  int wg = ((int)blockIdx.x & 7) * cq + ((int)blockIdx.x >> 3);
  int tm = wg / ntn, tn = wg % ntn;

  int tid = threadIdx.x, lane = tid & 63, w = tid >> 6;
  int wm = w / WN, wn = w % WN;
  int l15 = lane & 15, l4 = lane >> 4;

  f32x4 zero = {0.f, 0.f, 0.f, 0.f};
  f32x4 acc[RM][RN];
  #pragma unroll
  for(int m = 0; m < RM; m++)
    #pragma unroll
    for(int n = 0; n < RN; n++) acc[m][n] = zero;

  int srow = tid >> 3, scol = (tid & 7) * 8;
  const u16* Ag = A  + ((size_t)tm*BM + srow)*(size_t)K + scol;
  const u16* Bg = Bt + ((size_t)tn*BN + srow)*(size_t)K + scol;
  int ldsAo = srow*64 + scol;
  int ldsBo = BM*64 + srow*64 + scol;

  int NT = K >> 6;
  // prologue: stage K-tile 0 into buffer 0
  #pragma unroll
  for(int p = 0; p < PA; p++) gll16(Ag + (size_t)p*RSTEP*K, lds + ldsAo + p*RSTEP*64);
  #pragma unroll
  for(int p = 0; p < PB; p++) gll16(Bg + (size_t)p*RSTEP*K, lds + ldsBo + p*RSTEP*64);
  __syncthreads();

  int wr = wm * (BM/WM), wc = wn * (BN/WN);
  for(int t = 0; t < NT; t++){
    const u16* buf = lds + (t & 1) * LDSH;
    if(t + 1 < NT){
      u16* nbuf = lds + ((t + 1) & 1) * LDSH;
      int kt = (t + 1) << 6;
      #pragma unroll
      for(int p = 0; p < PA; p++) gll16(Ag + (size_t)p*RSTEP*K + kt, nbuf + ldsAo + p*RSTEP*64);
      #pragma unroll
      for(int p = 0; p < PB; p++) gll16(Bg + (size_t)p*RSTEP*K + kt, nbuf + ldsBo + p*RSTEP*64);
    }
    #pragma unroll
    for(int kc = 0; kc < 2; kc++){
      s16x8 af[RM], bfr[RN];
      #pragma unroll
      for(int m = 0; m < RM; m++) af[m]  = *(const s16x8*)(buf + (wr + m*16 + l15)*64 + kc*32 + l4*8);
      #pragma unroll
      for(int n = 0; n < RN; n++) bfr[n] = *(const s16x8*)(buf + BM*64 + (wc + n*16 + l15)*64 + kc*32 + l4*8);
      #pragma unroll
      for(int m = 0; m < RM; m++)
        #pragma unroll
        for(int n = 0; n < RN; n++)
          acc[m][n] = mfma_bf16(af[m], bfr[n], acc[m][n]);
    }
    __syncthreads();
  }

  int row0 = tm*BM + wr, col0 = tn*BN + wc;
  #pragma unroll
  for(int n = 0; n < RN; n++){
    int col = col0 + n*16 + l15;
    float bcol = bias[col];
    #pragma unroll
    for(int m = 0; m < RM; m++){
      #pragma unroll
      for(int b4 = 0; b4 < 4; b4++){
        int row = row0 + m*16 + l4*4 + b4;
        size_t oi = (size_t)row * N + col;
        float vout = acc[m][n][b4] + bcol;
        if constexpr (EPI == 1){
          float uu = 0.7978845608f * vout * (1.f + 0.044715f * vout * vout);
          float e  = __expf(2.f * uu);
          float th = 1.f - __fdividef(2.f, e + 1.f);
          Cb[oi] = f2bf(0.5f * vout * (1.f + th));
        } else {
          Cf[oi] = vout + resid[oi];
        }
      }
    }
  }
}

// ---------------- LayerNorm (row=1024), optional bf16 copy out --------------
__global__ __launch_bounds__(256) void ln_kernel(const float* __restrict__ a,
                                                 const float* __restrict__ w,
                                                 const float* __restrict__ bvec,
                                                 float* __restrict__ outf,
                                                 u16* __restrict__ outb,
                                                 int writeBf){
  int row = blockIdx.x;
  float4 val = ((const float4*)(a + (size_t)row * 1024))[threadIdx.x];
  float s  = val.x + val.y + val.z + val.w;
  float ss = val.x * val.x + val.y * val.y + val.z * val.z + val.w * val.w;
  #pragma unroll
  for(int off = 32; off > 0; off >>= 1){
    s  += __shfl_down(s, off);
    ss += __shfl_down(ss, off);
  }
  __shared__ float sb[8];
  int lane = threadIdx.x & 63, wv = threadIdx.x >> 6;
  if(lane == 0){ sb[wv] = s; sb[4 + wv] = ss; }
  __syncthreads();
  s  = sb[0] + sb[1] + sb[2] + sb[3];
  ss = sb[4] + sb[5] + sb[6] + sb[7];
  float mean = s * (1.f / 1024.f);
  float var  = ss * (1.f / 1024.f) - mean * mean;
  float rstd = rsqrtf(var + 1e-5f);
  int c = threadIdx.x * 4;
  float4 w4 = *(const float4*)(w + c);
  float4 b4 = *(const float4*)(bvec + c);
  float4 o4;
  o4.x = (val.x - mean) * rstd * w4.x + b4.x;
  o4.y = (val.y - mean) * rstd * w4.y + b4.y;
  o4.z = (val.z - mean) * rstd * w4.z + b4.z;
  o4.w = (val.w - mean) * rstd * w4.w + b4.w;
  ((float4*)(outf + (size_t)row * 1024))[threadIdx.x] = o4;
  if(writeBf){
    ushort4 ob = { f2bf(o4.x), f2bf(o4.y), f2bf(o4.z), f2bf(o4.w) };
    *(ushort4*)(outb + (size_t)row * 1024 + c) = ob;
  }
}

// ---------------------------------------------------------------------------
extern "C" void kernel_launch(void* const* d_in, const int* in_sizes, int n_in,
                              void* d_out, int out_size, void* d_ws, size_t ws_size,
                              hipStream_t stream){
  const float* x    = (const float*)d_in[0];
  const float* wq   = (const float*)d_in[1];
  const float* bq   = (const float*)d_in[2];
  const float* wk   = (const float*)d_in[3];
  const float* bk   = (const float*)d_in[4];
  const float* wv   = (const float*)d_in[5];
  const float* bv   = (const float*)d_in[6];
  const float* wo   = (const float*)d_in[7];
  const float* bo   = (const float*)d_in[8];
  const float* ln1w = (const float*)d_in[9];
  const float* ln1b = (const float*)d_in[10];
  const float* w1   = (const float*)d_in[11];
  const float* b1   = (const float*)d_in[12];
  const float* w2   = (const float*)d_in[13];
  const float* b2   = (const float*)d_in[14];
  const float* ln2w = (const float*)d_in[15];
  const float* ln2b = (const float*)d_in[16];
  float* out = (float*)d_out;

  char* ws8 = (char*)d_ws;
  u16*   qb  = (u16*)  (ws8 + ((size_t)0   << 20));  // 16 MiB  [B][H][S][64]
  u16*   kb  = (u16*)  (ws8 + ((size_t)16  << 20));  // 16 MiB
  u16*   vb  = (u16*)  (ws8 + ((size_t)32  << 20));  // 16 MiB  V^T [B][H][64][S]
  u16*   ob  = (u16*)  (ws8 + ((size_t)48  << 20));  // 16 MiB  [B*S][1024]
  u16*   wot = (u16*)  (ws8 + ((size_t)64  << 20));  //  2 MiB  [1024][1024]
  u16*   w1t = (u16*)  (ws8 + ((size_t)66  << 20));  //  8 MiB  [4096][1024]
  u16*   w2t = (u16*)  (ws8 + ((size_t)74  << 20));  //  8 MiB  [1024][4096]
  u16*   tb  = (u16*)  (ws8 + ((size_t)82  << 20));  // 16 MiB  t bf16
  u16*   gb  = (u16*)  (ws8 + ((size_t)98  << 20));  // 64 MiB  g bf16 [8192][4096]
  float* rr  = (float*)(ws8 + ((size_t)162 << 20));  // 32 MiB  r1 then r2
  float* tf  = (float*)(ws8 + ((size_t)194 << 20));  // 32 MiB  t f32

  transpose_cast<<<dim3(32, 32),  256, 0, stream>>>(wo, wot, 1024, 1024);
  transpose_cast<<<dim3(128, 32), 256, 0, stream>>>(w1, w1t, 1024, 4096);
  transpose_cast<<<dim3(32, 128), 256, 0, stream>>>(w2, w2t, 4096, 1024);

  qkv_kernel<<<dim3(256, 16), 256, 0, stream>>>(x, wq, bq, wk, bk, wv, bv, qb, kb, vb);
  attn_kernel<<<dim3(512), 256, 0, stream>>>(qb, kb, vb, ob);

  // r1 = o @ wo + bo + x            (M=8192, N=1024, K=1024) 128² tiles
  gemm_dbuf<0,128,128,2,2><<<dim3(512), 256, 0, stream>>>(ob, wot, bo, x, rr, nullptr, 8192, 1024, 1024, 8);
  // t = LN1(r1)
  ln_kernel<<<dim3(8192), 256, 0, stream>>>(rr, ln1w, ln1b, tf, tb, 1);
  // g = gelu(t @ w1 + b1)           (M=8192, N=4096, K=1024) 256² tiles
  gemm_dbuf<1,256,256,2,4><<<dim3(512), 512, 0, stream>>>(tb, w1t, b1, nullptr, nullptr, gb, 8192, 4096, 1024, 16);
  // r2 = g @ w2 + b2 + t            (M=8192, N=1024, K=4096) 128² tiles
  gemm_dbuf<2,128,128,2,2><<<dim3(512), 256, 0, stream>>>(gb, w2t, b2, tf, rr, nullptr, 8192, 1024, 4096, 8);
  // out = LN2(r2)
  ln_kernel<<<dim3(8192), 256, 0, stream>>>(rr, ln2w, ln2b, out, nullptr, 0);
}